// Round 13
// baseline (57.119 us; speedup 1.0000x reference)
//
#include <hip/hip_runtime.h>
#include <cmath>

// Sampler: temperature(0.7) -> top-p(0.9, HF semantics) -> top-k(50)
// -> softmax -> inverse-CDF multinomial with given uniform u.
//
// R13: 3 kernels, Z folded into the max pass via per-thread ONLINE logsumexp
// (flash-style running-max rescale; no anchor dependency), so pass 2 is a
// lean collect-only stream (1 fmax compare/elem) over L3-hot data.
// K1 mz: per-seg exact max + Z partial (online, per-seg anchor).
// K2 collect: window l > M-5 (M exact from K1) -> per-(row,seg64) slots.
// K3 finish: R12-validated (Z rescale to global anchor, atomic-compaction
// gather + hist, suffix-scan threshold, all-pairs rank, exact-path exp,
// sequential nucleus + CDF).

constexpr int   NSPLIT = 32;             // K1 segments/row
constexpr int   NSEGC  = 64;             // K2 segments/row
constexpr int   BLK    = 256;
constexpr int   NBINS  = 1024;
constexpr int   BPL    = NBINS / 64;
constexpr int   TOPK   = 50;
constexpr float TEMP   = 0.7f;
constexpr float SPANC  = 5.0f;           // collect/hist window below global max
constexpr int   CAPSG  = 64;             // slots per (row,seg64)
constexpr int   NCANDC = NSEGC * CAPSG;  // 4096 slots/row
constexpr int   BLK_F  = 256;
constexpr int   NDENSE = 2048;           // dense filtered-candidate cap (LDS)
constexpr int   CAPC   = 128;            // compacted survivors cap
// exp((l-M)/T) == exp2((l-M) * LOG2E_OVER_T)
constexpr float LOG2E_OVER_T = (float)(1.4426950408889634 / 0.7);

// ---------------- K1: max + online-logsumexp Z, one streaming read --------
__global__ __launch_bounds__(BLK)
void mz_kernel(const float* __restrict__ logits,
               float* __restrict__ segmax, float* __restrict__ segz,
               int V, int seglen)
{
  const int seg  = blockIdx.x;
  const int row  = blockIdx.y;
  const int tid  = threadIdx.x, lane = tid & 63, wave = tid >> 6;
  const int start = seg * seglen;
  const int len  = (V - start < seglen) ? (V - start) : seglen;

  __shared__ float redm[BLK / 64];
  __shared__ float redz[BLK / 64];

  if (len <= 0) {
    if (tid == 0) { segmax[row * NSPLIT + seg] = -INFINITY;
                    segz  [row * NSPLIT + seg] = 0.f; }
    return;
  }

  const float* __restrict__ base = logits + (size_t)row * V + start;
  const int len4 = len >> 2;
  const float4* b4 = reinterpret_cast<const float4*>(base);
  const float k = LOG2E_OVER_T;

  float tm = -INFINITY;   // per-thread running max
  float tz = 0.f;         // per-thread Z partial anchored at tm

  for (int i = tid; i < len4; i += BLK) {
    float4 a = b4[i];
    float lm = fmaxf(fmaxf(a.x, a.y), fmaxf(a.z, a.w));
    if (lm > tm) {                       // rare after warmup (~ln(n) times)
      tz *= exp2f((tm - lm) * k);        // tm=-inf -> exp2f(-inf)=0 -> tz=0
      tm = lm;
    }
    float e0 = exp2f((a.x - tm) * k);
    float e1 = exp2f((a.y - tm) * k);
    float e2 = exp2f((a.z - tm) * k);
    float e3 = exp2f((a.w - tm) * k);
    tz += (e0 + e1) + (e2 + e3);
  }
  for (int i = (len4 << 2) + tid; i < len; i += BLK) {
    float l = base[i];
    if (l > tm) { tz *= exp2f((tm - l) * k); tm = l; }
    tz += exp2f((l - tm) * k);
  }

  // wave combine (online-softmax pairwise merge)
  #pragma unroll
  for (int off = 32; off >= 1; off >>= 1) {
    float om = __shfl_xor(tm, off, 64);
    float oz = __shfl_xor(tz, off, 64);
    float mn = fmaxf(tm, om);
    if (mn > -INFINITY)
      tz = tz * exp2f((tm - mn) * k) + oz * exp2f((om - mn) * k);
    else
      tz = 0.f;
    tm = mn;
  }
  if (lane == 0) { redm[wave] = tm; redz[wave] = tz; }
  __syncthreads();
  if (tid == 0) {
    float m = redm[0], z = redz[0];
    for (int w = 1; w < BLK / 64; ++w) {
      float om = redm[w], oz = redz[w];
      float mn = fmaxf(m, om);
      if (mn > -INFINITY)
        z = z * exp2f((m - mn) * k) + oz * exp2f((om - mn) * k);
      else
        z = 0.f;
      m = mn;
    }
    segmax[row * NSPLIT + seg] = m;      // exact segment max
    segz  [row * NSPLIT + seg] = z;      // Z partial anchored at m
  }
}

// ---------------- K2: collect-only stream (L3-hot) -------------------------
__global__ __launch_bounds__(BLK)
void collect_kernel(const float* __restrict__ logits,
                    const float* __restrict__ segmax,
                    float* __restrict__ cand_v, int* __restrict__ cand_i,
                    unsigned int* __restrict__ cntc,
                    int V, int seglen)
{
  const int seg  = blockIdx.x;
  const int row  = blockIdx.y;
  const int tid  = threadIdx.x, lane = tid & 63;
  const int start = seg * seglen;
  const int len  = (V - start < seglen) ? (V - start) : seglen;

  __shared__ unsigned int s_nf;

  if (len <= 0) { if (tid == 0) cntc[row * NSEGC + seg] = 0u; return; }

  // global row max: each wave independently reduces the 32 K1 seg maxes
  float sm = (lane < NSPLIT) ? segmax[row * NSPLIT + lane] : -INFINITY;
  #pragma unroll
  for (int off = 32; off >= 1; off >>= 1) sm = fmaxf(sm, __shfl_xor(sm, off, 64));
  const float lo = sm - SPANC;

  if (tid == 0) s_nf = 0u;
  __syncthreads();

  float* cvout = cand_v + ((size_t)row * NSEGC + seg) * CAPSG;
  int*   ciout = cand_i + ((size_t)row * NSEGC + seg) * CAPSG;

  const float* __restrict__ base = logits + (size_t)row * V + start;
  const int len4 = len >> 2;
  const float4* b4 = reinterpret_cast<const float4*>(base);

  for (int i = tid; i < len4; i += BLK) {
    float4 a = b4[i];
    float lm = fmaxf(fmaxf(a.x, a.y), fmaxf(a.z, a.w));
    if (lm > lo) {                        // rare: ~300/row total
      #pragma unroll
      for (int c = 0; c < 4; ++c) {
        float l = (c == 0) ? a.x : (c == 1) ? a.y : (c == 2) ? a.z : a.w;
        if (l > lo) {
          unsigned int p = atomicAdd(&s_nf, 1u);
          if (p < CAPSG) { cvout[p] = l; ciout[p] = start + (i << 2) + c; }
        }
      }
    }
  }
  for (int i = (len4 << 2) + tid; i < len; i += BLK) {
    float l = base[i];
    if (l > lo) {
      unsigned int p = atomicAdd(&s_nf, 1u);
      if (p < CAPSG) { cvout[p] = l; ciout[p] = start + i; }
    }
  }
  __syncthreads();
  if (tid == 0) {
    unsigned int nf = s_nf;
    cntc[row * NSEGC + seg] = (nf > CAPSG) ? (unsigned)CAPSG : nf;
  }
}

// ---------------- K3: finish (R12-validated machinery) ---------------------
__global__ __launch_bounds__(BLK_F)
void finish_kernel(const float* __restrict__ segmax, const float* __restrict__ segz,
                   const float* __restrict__ cand_v, const int* __restrict__ cand_i,
                   const unsigned int* __restrict__ cntc,
                   const float* __restrict__ uvec, int* __restrict__ out)
{
  const int row  = blockIdx.x;
  const int tid  = threadIdx.x;
  const int lane = tid & 63;
  const int wave = tid >> 6;
  const float invT = 1.0f / TEMP;

  __shared__ unsigned int hist[NBINS];
  __shared__ unsigned int chunk[64];
  __shared__ unsigned int cnt_s[NSEGC];
  __shared__ float s_M, s_Z;
  __shared__ int   s_bstar;
  __shared__ unsigned int s_nd;    // dense filtered count
  __shared__ unsigned int s_nc;    // survivor count
  __shared__ float dn_v[NDENSE];
  __shared__ int   dn_i[NDENSE];
  __shared__ float fv[CAPC];
  __shared__ int   fi[CAPC];
  __shared__ float ov_[CAPC];     // rank-ordered values
  __shared__ int   oi_[CAPC];     // rank-ordered indices
  __shared__ float eo[64];        // e per rank
  __shared__ float o2e[64];       // index-sorted kept e
  __shared__ int   o2i[64];
  __shared__ int   s_nk;

  if (tid < NSEGC) cnt_s[tid] = cntc[row * NSEGC + tid];
  for (int i = tid; i < NBINS; i += BLK_F) hist[i] = 0u;
  __syncthreads();

  if (tid < 64) {
    float sm = (lane < NSPLIT) ? segmax[row * NSPLIT + lane] : -INFINITY;
    float m = sm;
    #pragma unroll
    for (int off = 32; off >= 1; off >>= 1) m = fmaxf(m, __shfl_xor(m, off, 64));
    // rescale per-seg-anchored Z partials to the global max (validated R12)
    float zt = (lane < NSPLIT) ? segz[row * NSPLIT + lane] * expf((sm - m) * invT) : 0.f;
    #pragma unroll
    for (int off = 32; off >= 1; off >>= 1) zt += __shfl_xor(zt, off, 64);
    if (lane == 0) { s_M = m; s_Z = zt; s_nd = 0u; s_nc = 0u; }
  }
  __syncthreads();

  const float M  = s_M;
  const float lo = M - SPANC;
  const float binscale = (float)NBINS / SPANC;
  const float* cvrow = cand_v + (size_t)row * NCANDC;
  const int*   cirow = cand_i + (size_t)row * NCANDC;

  // gather candidates (window filter is tautologically true here; kept for
  // safety) + histogram in the same pass. wave w handles segs w, w+4, ...
  for (int sg = wave; sg < NSEGC; sg += BLK_F / 64) {
    const unsigned int c = cnt_s[sg];
    for (unsigned int i = lane; i < c; i += 64) {
      float v = cvrow[sg * CAPSG + i];
      if (v > lo) {
        unsigned int d = atomicAdd(&s_nd, 1u);
        if (d < (unsigned)NDENSE) {
          dn_v[d] = v;
          dn_i[d] = cirow[sg * CAPSG + i];
          int b = (int)((v - lo) * binscale);
          b = (b < 0) ? 0 : ((b > NBINS - 1) ? (NBINS - 1) : b);
          atomicAdd(&hist[b], 1u);
        }
      }
    }
  }
  __syncthreads();
  const int n = ((int)s_nd < NDENSE) ? (int)s_nd : NDENSE;

  if (tid < 64) {
    unsigned int csum = 0;
    const int cb = tid * BPL;
    #pragma unroll
    for (int j = 0; j < BPL; ++j) csum += hist[cb + j];
    chunk[tid] = csum;
  }
  __syncthreads();
  if (tid < 64) {
    unsigned int csum = chunk[tid];
    unsigned int suf = 0;
    for (int l2 = 0; l2 < 64; ++l2) {
      unsigned int c2 = chunk[l2];
      suf += (l2 >= tid) ? c2 : 0u;
    }
    unsigned long long bal = __ballot(suf >= (unsigned)TOPK);
    if (bal == 0ull) {
      if (tid == 0) s_bstar = 0;
    } else {
      int L = 63 - __builtin_clzll(bal);
      if (tid == L) {
        unsigned int running = suf - csum;
        const int cb = tid * BPL;
        unsigned int h[BPL];
        #pragma unroll
        for (int j = 0; j < BPL; ++j) h[j] = hist[cb + j];
        int bsel = cb;
        #pragma unroll
        for (int j = BPL - 1; j >= 0; --j) {
          running += h[j];
          if (running >= (unsigned)TOPK) { bsel = cb + j; break; }
        }
        s_bstar = bsel;
      }
    }
  }
  __syncthreads();

  // compact survivors (bin >= bstar) from dense array
  const int bstar = s_bstar;
  for (int i = tid; i < n; i += BLK_F) {
    float v = dn_v[i];
    int b = (int)((v - lo) * binscale);
    b = (b < 0) ? 0 : ((b > NBINS - 1) ? (NBINS - 1) : b);
    if (b >= bstar) {
      unsigned int p = atomicAdd(&s_nc, 1u);
      if (p < CAPC) { fv[p] = v; fi[p] = dn_i[i]; }
    }
  }
  __syncthreads();

  // all-pairs descending rank (value desc, index asc) + scatter
  const int ns = ((int)s_nc < CAPC) ? (int)s_nc : CAPC;
  if (tid < 64) {
    float c0v = (lane < ns)      ? fv[lane]      : 0.f;
    int   c0i = (lane < ns)      ? fi[lane]      : 0;
    float c1v = (lane + 64 < ns) ? fv[lane + 64] : 0.f;
    int   c1i = (lane + 64 < ns) ? fi[lane + 64] : 0;
    int r0 = 0, r1 = 0;
    for (int j = 0; j < ns; ++j) {
      float vj = fv[j]; int ij = fi[j];
      if (vj > c0v || (vj == c0v && ij < c0i)) ++r0;
      if (vj > c1v || (vj == c1v && ij < c1i)) ++r1;
    }
    if (lane < ns)      { ov_[r0] = c0v; oi_[r0] = c0i; }
    if (lane + 64 < ns) { ov_[r1] = c1v; oi_[r1] = c1i; }
  }
  __syncthreads();

  // per-rank exp on the exact reference path
  const float Mx = M / TEMP;                 // fl(M/0.7)
  if (tid < 64 && lane < ns && lane < TOPK) {
    float x = ov_[lane] / TEMP;              // fl(v/0.7) per element
    eo[lane] = expf(x - Mx);
  }
  __syncthreads();

  // sequential fp32 nucleus scan (lane 0)
  if (tid == 0) {
    const float thresh = 0.9f * s_Z;
    const int nkmax = (ns < TOPK) ? ns : TOPK;
    float cum = 0.f; int nk = 0;
    for (int kk = 0; kk < TOPK; ++kk) {
      float ek = eo[kk];
      bool take = (kk < nkmax) && (cum < thresh);
      if (take) { cum += ek; nk++; }
    }
    s_nk = nk;
  }
  __syncthreads();

  // rank kept tokens by original index
  const int nk = s_nk;
  if (tid < 64 && lane < nk) {
    int myi = oi_[lane];
    int rank = 0;
    for (int j = 0; j < nk; ++j) rank += (oi_[j] < myi) ? 1 : 0;
    o2e[rank] = eo[lane]; o2i[rank] = myi;
  }
  __syncthreads();

  // sequential CDF sample (lane 0)
  if (tid == 0) {
    float S = 0.f;
    for (int j = 0; j < nk; ++j) S += o2e[j];
    const float uu = uvec[row];
    float c = 0.f; int token = 0; int found = 0;
    for (int j = 0; j < nk; ++j) {
      float q = o2e[j] / S;                  // mirrors softmax per-element divide
      c += q;
      if (!found && c >= uu) { token = o2i[j]; found = 1; }
    }
    out[row] = token;
  }
}

extern "C" void kernel_launch(void* const* d_in, const int* in_sizes, int n_in,
                              void* d_out, int out_size, void* d_ws, size_t ws_size,
                              hipStream_t stream) {
  const float* logits = (const float*)d_in[0];
  // d_in[1] = input_ids (unused: repetition_penalty == 1.0)
  const float* u = (const float*)d_in[2];
  int* out = (int*)d_out;
  const int B = in_sizes[2];
  const int V = in_sizes[0] / B;
  int seglen1 = (V + NSPLIT - 1) / NSPLIT; seglen1 = (seglen1 + 3) & ~3;
  int seglenC = (V + NSEGC - 1) / NSEGC;   seglenC = (seglenC + 3) & ~3;

  // workspace layout (4-byte aligned):
  char* ws = (char*)d_ws;
  float* segmax = (float*)ws;                                   // B*NSPLIT
  float* segz   = segmax + (size_t)B * NSPLIT;                  // B*NSPLIT
  unsigned int* cntc = (unsigned int*)(segz + (size_t)B * NSPLIT); // B*NSEGC
  float* cand_v = (float*)(cntc + (size_t)B * NSEGC);           // B*NCANDC
  int*   cand_i = (int*)(cand_v + (size_t)B * NCANDC);          // B*NCANDC

  mz_kernel<<<dim3(NSPLIT, B), dim3(BLK), 0, stream>>>(
      logits, segmax, segz, V, seglen1);
  collect_kernel<<<dim3(NSEGC, B), dim3(BLK), 0, stream>>>(
      logits, segmax, cand_v, cand_i, cntc, V, seglenC);
  finish_kernel<<<dim3(B), dim3(BLK_F), 0, stream>>>(
      segmax, segz, cand_v, cand_i, cntc, u, out);
}